// Round 12
// baseline (32.846 us; speedup 1.0000x reference)
//
#include <hip/hip_runtime.h>
#include <math.h>

#define NC 2048            // 2H + 2W (H = W = 512)
#define NB 4
#define NS 4096
#define INV_TEMP (1.0f / 256.0f)
#define LOG2E 1.44269504088896340736f
#define CL 32              // chunk length (rows per loss block)
#define NCH (NS / CL)      // 128 chunks per batch
#define P1_NG 16           // scan groups per P1 block (512 thr / 32 ch)
#define P1_GS (NS / P1_NG) // 256 s per group
#define P1_GC (P1_GS / CL) // 8 chunks per group
#define LOSS_NBLK (NB * NCH)   // 512 loss blocks

typedef float f32x4 __attribute__((ext_vector_type(4)));
typedef float f32x2 __attribute__((ext_vector_type(2)));

// ---------------------------------------------------------------------------
// Phase 1: per-(b, 32-channel tile) block. p in {0,1} exactly -> pack each
// step as {dec, enc} (enc = hot in-segment channel if this segment active,
// else -1), then per-chunk suffix sums + hierarchical scan -> rstart.
// Inner loop reads PAIRS of steps via one f32x4 LDS read (b128, broadcast).
// ---------------------------------------------------------------------------
__global__ __launch_bounds__(512) void tdl_scan_kernel(
    const float* __restrict__ target, float* __restrict__ rstart)
{
    const int b     = blockIdx.x >> 6;   // 64 channel-tiles per batch
    const int ctile = blockIdx.x & 63;
    const int tid = threadIdx.x;
    const int ci  = tid & 31;            // channel within tile
    const int g   = tid >> 5;            // scan group (0..15)

    __shared__ float shbuf[NS * 4];      // 64 KB: f32x4 ev[NS] then f32x2 pk[NS]
    __shared__ float shL[P1_NG][32];
    __shared__ float shG[P1_NG];
    f32x4* ev = (f32x4*)shbuf;
    f32x2* pk = (f32x2*)shbuf;

    const int  seg    = ctile >> 4;                       // 0..3
    const bool useH   = (seg < 2);
    const float segPar = (float)(seg & 1);
    const float crel  = (float)(((ctile & 15) << 5) + ci); // in-segment channel

    const float* tb = target + (size_t)b * NS * 4;

    // 1. stage target[b] as f32x4 {t,h,w,p}
#pragma unroll
    for (int m = 0; m < 8; ++m) {
        int s = m * 512 + tid;
        ev[s] = *((const f32x4*)tb + s);
    }
    __syncthreads();

    // 2. compute {dec, enc} in regs + my chunk alphas + group G (reads only)
    float dec_r[8], enc_r[8];
#pragma unroll
    for (int m = 0; m < 8; ++m) {
        int s = m * 512 + tid;
        f32x4 e = ev[s];
        dec_r[m] = (s == NS - 1) ? 0.0f
                  : __expf(-(ev[s + 1].x - e.x) * INV_TEMP);
        enc_r[m] = (e.w == segPar) ? (useH ? e.y : e.z) : -1.0f;
    }
    float alp[P1_GC];
    {
        const int gs = g * P1_GS;
#pragma unroll
        for (int q = 0; q < P1_GC; ++q) {
            int se = gs + q * CL;
            alp[q] = (g == P1_NG - 1 && q == P1_GC - 1) ? 0.0f
                     : __expf(-(ev[se + CL].x - ev[se].x) * INV_TEMP);
        }
        if (ci == 0) {
            shG[g] = (g == P1_NG - 1) ? 0.0f
                     : __expf(-(ev[gs + P1_GS].x - ev[gs].x) * INV_TEMP);
        }
    }
    __syncthreads();

    // 3. overwrite buffer with packed float2
#pragma unroll
    for (int m = 0; m < 8; ++m) {
        int s = m * 512 + tid;
        f32x2 v; v.x = dec_r[m]; v.y = enc_r[m];
        pk[s] = v;
    }
    __syncthreads();

    // 4. per-chunk local suffix sums (zero carry); paired b128 reads
    float cs[P1_GC];
    {
        const int gs = g * P1_GS;
#pragma unroll
        for (int q = P1_GC - 1; q >= 0; --q) {
            float v = 0.0f;
            const int base = gs + q * CL;
#pragma unroll
            for (int i = CL - 2; i >= 0; i -= 2) {
                f32x4 e2 = *(const f32x4*)&pk[base + i]; // {d_i,e_i,d_i1,e_i1}
                v = fmaf(v, e2.z, (e2.w == crel) ? 1.0f : 0.0f);  // step i+1
                v = fmaf(v, e2.x, (e2.y == crel) ? 1.0f : 0.0f);  // step i
            }
            cs[q] = v;
        }
    }

    // 5. group-local combine -> L (value at group start, zero incoming)
    float L = 0.0f;
#pragma unroll
    for (int q = P1_GC - 1; q >= 0; --q) L = fmaf(alp[q], L, cs[q]);
    shL[g][ci] = L;
    __syncthreads();

    // 6. carry into group g = suffix over groups j > g
    float X = 0.0f;
#pragma unroll
    for (int j = P1_NG - 1; j >= 1; --j)
        if (j > g) X = fmaf(shG[j], X, shL[j][ci]);

    // 7. chunk-level replay with carry, store rstart[b, g*8+q, c]
    float* rs = rstart + ((size_t)b * NCH + g * P1_GC) * NC + (ctile * 32 + ci);
    float carry = X;
#pragma unroll
    for (int q = P1_GC - 1; q >= 0; --q) {
        carry = fmaf(alp[q], carry, cs[q]);
        rs[(size_t)q * NC] = carry;
    }
}

// ---------------------------------------------------------------------------
// Phase 2: fused scan + soft-CE loss, ACTIVE-SEGMENT ONLY. 512 blocks x
// 4 waves; wv = H-pair/W-pair, rh=0 -> rows 31..16 (carry from rstart[k+1]),
// rh=1 -> rows 15..0 after a 16-row scan-only replay.
// Head-latency fixes: f32x4 ev staging; early global p-loads so the first
// two pred prefetches issue BEFORE the staging barrier; wave-uniform pv
// branch in the row body (no per-element cndmask select).
// ---------------------------------------------------------------------------
__global__ __launch_bounds__(256) void tdl_loss_kernel(
    const float* __restrict__ pred, const float* __restrict__ target,
    const float* __restrict__ rstart, float* __restrict__ partials)
{
    const int blk = blockIdx.x;
    const int b = blk >> 7;              // / NCH
    const int k = blk & (NCH - 1);
    const int s0 = k * CL;
    const int tid = threadIdx.x;
    const int wv  = (tid >> 6) & 1;      // 0: H-pair, 1: W-pair
    const int rh  = tid >> 7;            // 0: rows 31..16, 1: rows 15..0
    const int ln  = tid & 63;

    __shared__ f32x4 evraw[CL + 1];      // staged {t,h,w,p}
    __shared__ f32x4 ev[CL];             // {dec, p, h, w}
    __shared__ float sh4[4];

    const int lc   = ln * 4;             // lane offset within a 256-ch quarter
    const int segA = wv * 2;             // even segment of my pair
    const size_t pbase = (size_t)b * NS * NC;
    const int itop = rh ? (CL / 2 - 1) : (CL - 1);  // 15 or 31

    // EARLY: p for my first two rows straight from global (independent of
    // LDS staging) -> first two pred prefetches issue before the barrier.
    const float pt0 = target[((size_t)b * NS + s0 + itop) * 4 + 3];
    const float pt1 = target[((size_t)b * NS + s0 + itop - 1) * 4 + 3];

    f32x4 pf0[2], pf1[2];
    {
        const float* pr = pred + pbase + (size_t)(s0 + itop) * NC
                          + (segA + (int)pt0) * 512 + lc;
        pf0[0] = *(const f32x4*)pr; pf0[1] = *(const f32x4*)(pr + 256);
        const float* pr2 = pred + pbase + (size_t)(s0 + itop - 1) * NC
                           + (segA + (int)pt1) * 512 + lc;
        pf1[0] = *(const f32x4*)pr2; pf1[1] = *(const f32x4*)(pr2 + 256);
    }

    // carry init = r[b,(k+1)*CL, my channels] (zero for last chunk) — also
    // issued before staging completes (no LDS dependency)
    float vA[8], vB[8];
    if (k == NCH - 1) {
#pragma unroll
        for (int j = 0; j < 8; ++j) { vA[j] = 0.0f; vB[j] = 0.0f; }
    } else {
        const float* rrow = rstart + ((size_t)b * NCH + k + 1) * NC;
#pragma unroll
        for (int q = 0; q < 2; ++q) {
            f32x4 ra = *(const f32x4*)(rrow + segA * 512 + q * 256 + lc);
            f32x4 rb = *(const f32x4*)(rrow + (segA + 1) * 512 + q * 256 + lc);
#pragma unroll
            for (int j = 0; j < 4; ++j) {
                vA[q*4+j] = ra[j] * LOG2E;
                vB[q*4+j] = rb[j] * LOG2E;
            }
        }
    }

    // stage CL+1 raw event rows (vectorized f32x4, one round of 33 threads)
    if (tid <= CL) {
        int s = s0 + tid;
        if (s < NS) evraw[tid] = *((const f32x4*)target + (size_t)b * NS + s);
        else        { f32x4 z = {0,0,0,0}; evraw[tid] = z; }
    }
    __syncthreads();
    if (tid < CL) {
        f32x4 r = evraw[tid];
        int s = s0 + tid;
        float dec = (s == NS - 1 || s == 0) ? 0.0f
                   : __expf(-(evraw[tid + 1].x - r.x) * INV_TEMP);
        f32x4 e; e.x = dec; e.y = r.w; e.z = r.y; e.w = r.z;  // {dec,p,h,w}
        ev[tid] = e;
    }
    __syncthreads();

    // rh=1 waves: replay rows 31..16 scan-only to derive carry at row 15
    if (rh) {
#pragma unroll
        for (int i = CL - 1; i >= CL / 2; --i) {
            f32x4 e = ev[i];
            const float d    = e.x;
            const float pv   = e.y;
            const float idxf = wv ? e.w : e.z;
            const float aA = (1.0f - pv) * LOG2E;
            const float aB = pv * LOG2E;
#pragma unroll
            for (int q = 0; q < 2; ++q) {
#pragma unroll
                for (int j = 0; j < 4; ++j) {
                    const int id = q * 4 + j;
                    const float myc = (float)(q * 256 + lc + j);
                    const bool m = (idxf == myc);
                    vA[id] = fmaf(vA[id], d, m ? aA : 0.0f);
                    vB[id] = fmaf(vB[id], d, m ? aB : 0.0f);
                }
            }
        }
    }

    float acc = 0.0f;
#pragma unroll
    for (int i = itop; i > itop - CL / 2; --i) {
        f32x4 cur[2];
        cur[0] = pf0[0]; cur[1] = pf0[1];
        pf0[0] = pf1[0]; pf0[1] = pf1[1];
        if (i >= itop - (CL / 2 - 3)) {  // row i-2 still in my range
            const int pa = (int)ev[i - 2].y;
            const float* pr = pred + pbase + (size_t)(s0 + i - 2) * NC
                              + (segA + pa) * 512 + lc;
            pf1[0] = *(const f32x4*)pr; pf1[1] = *(const f32x4*)(pr + 256);
        }

        f32x4 e = ev[i];
        const float d    = e.x;
        const float pv   = e.y;                    // 0.0 or 1.0 exactly
        const float idxf = wv ? e.w : e.z;         // w for W-pair, h for H-pair
        const float aA = (1.0f - pv) * LOG2E;
        const float aB = pv * LOG2E;

        // scan update for both segments (always)
#pragma unroll
        for (int q = 0; q < 2; ++q) {
#pragma unroll
            for (int j = 0; j < 4; ++j) {
                const int id = q * 4 + j;
                const float myc = (float)(q * 256 + lc + j);
                const bool m = (idxf == myc);
                vA[id] = fmaf(vA[id], d, m ? aA : 0.0f);
                vB[id] = fmaf(vB[id], d, m ? aB : 0.0f);
            }
        }

        // loss body for the ACTIVE segment only (wave-uniform branch)
        float ser = 0.0f, dot = 0.0f, sep = 0.0f;
#define ROW_BODY(V)                                                        \
        _Pragma("unroll")                                                  \
        for (int q = 0; q < 2; ++q) {                                      \
            _Pragma("unroll")                                              \
            for (int j = 0; j < 4; ++j) {                                  \
                const float ex = exp2f(V[q * 4 + j]);                      \
                const float pj = cur[q][j];                                \
                ser += ex;                                                 \
                dot = fmaf(ex, pj, dot);                                   \
                sep += __expf(pj);                                         \
            }                                                              \
        }
        if (pv != 0.0f) { ROW_BODY(vB) } else { ROW_BODY(vA) }
#undef ROW_BODY

        // full-wave 64-lane reductions (active segment = 512 ch = 64 x 8)
#pragma unroll
        for (int off = 32; off > 0; off >>= 1) {
            ser += __shfl_xor(ser, off, 64);
            dot += __shfl_xor(dot, off, 64);
            sep += __shfl_xor(sep, off, 64);
        }
        acc += __logf(sep) - dot * __builtin_amdgcn_rcpf(ser);
    }

    if (ln == 0) sh4[tid >> 6] = acc;    // one writer per wave
    __syncthreads();
    if (tid == 0) partials[blk] = sh4[0] + sh4[1] + sh4[2] + sh4[3];
}

// ---------------------------------------------------------------------------
// Phase 3: tiny reduce — 1 block, 256 threads, 2 KB of partials -> out[0].
// ---------------------------------------------------------------------------
__global__ __launch_bounds__(256) void tdl_reduce_kernel(
    const float* __restrict__ partials, float* __restrict__ out)
{
    const int tid = threadIdx.x;
    __shared__ float sh4[4];

    float s = 0.0f;
#pragma unroll
    for (int i = 0; i < LOSS_NBLK / 256; ++i)
        s += partials[i * 256 + tid];
#pragma unroll
    for (int off = 32; off > 0; off >>= 1)
        s += __shfl_xor(s, off, 64);
    if ((tid & 63) == 0) sh4[tid >> 6] = s;
    __syncthreads();
    if (tid == 0)
        out[0] = (sh4[0] + sh4[1] + sh4[2] + sh4[3])
                 * (1.0f / ((float)NB * (float)NS));
}

// ---------------------------------------------------------------------------
extern "C" void kernel_launch(void* const* d_in, const int* in_sizes, int n_in,
                              void* d_out, int out_size, void* d_ws, size_t ws_size,
                              hipStream_t stream)
{
    const float* pred   = (const float*)d_in[0];
    const float* target = (const float*)d_in[1];
    float* out    = (float*)d_out;
    float* rstart = (float*)d_ws;                       // 4 MiB
    float* partials = rstart + (size_t)NB * NCH * NC;   // 2 KiB

    tdl_scan_kernel<<<NB * 64, 512, 0, stream>>>(target, rstart);
    tdl_loss_kernel<<<NB * NCH, 256, 0, stream>>>(pred, target, rstart, partials);
    tdl_reduce_kernel<<<1, 256, 0, stream>>>(partials, out);
}